// Round 3
// baseline (569.976 us; speedup 1.0000x reference)
//
#include <hip/hip_runtime.h>
#include <math.h>

// Problem constants
constexpr int BB = 2048;     // batch
constexpr int CC = 129;      // channels
constexpr int TT = 200;      // time
constexpr int NPAIR = BB * CC;          // 264192
constexpr int PPB = 64;                 // pairs per block in kA (lane = pair)
// x row stride in dwords: multiple of 4 (16B-aligned rows for b128 write/read)
// and 204 mod 32 = 12 gives uniform bank coverage for lane-per-row b128 reads.
constexpr int XSTR = 204;

// d_ws layout (in floats)
constexpr int OFF_AVG = 8192;                    // tab occupies 30*100*2 = 6000 floats
constexpr int OFF_MX  = OFF_AVG + NPAIR;
constexpr int OFF_FT  = OFF_MX + NPAIR;          // NPAIR*4 floats

// ---------------------------------------------------------------------------
// Init: windowed DFT table, tab[k-1][t] = (w[t]*cos(2pi*k*t/100), w[t]*sin(...)).
// ---------------------------------------------------------------------------
__global__ void kInit(float2* __restrict__ tab) {
    int i = blockIdx.x * 256 + threadIdx.x;
    if (i >= 3000) return;
    int r = i / 100, t = i % 100;
    int ph = ((r + 1) * t) % 100;                 // exact mod-100 reduction
    const float C = 0.06283185307179587f;         // 2*pi/100
    float w = 0.5f - 0.5f * cosf(C * (float)t);
    float ang = C * (float)ph;
    tab[i] = make_float2(w * cosf(ang), w * sinf(ang));
}

// ---------------------------------------------------------------------------
// DFT worker: one wave handles bins KB..KB+NB-1 for 64 pairs (lane = pair).
// Table reads are wave-uniform (LDS broadcast). Branch-free unrolled body:
// all LDS addresses are base + immediate offsets.
// ---------------------------------------------------------------------------
template<int KB, int NB>
__device__ __forceinline__ void dft_wave(const float* __restrict__ xp,
                                         const float* __restrict__ tbf,
                                         float* __restrict__ bs,
                                         float mu0, float mu1, float mu2) {
    const float* trow = tbf + (KB - 1) * 200;     // 200 floats (100 float2) per bin
    float re[NB][3], im[NB][3];
    #pragma unroll
    for (int b = 0; b < NB; b++)
        #pragma unroll
        for (int s = 0; s < 3; s++) { re[b][s] = 0.f; im[b][s] = 0.f; }

    #pragma unroll 5
    for (int t0 = 0; t0 < 100; t0 += 4) {
        float4 a  = *(const float4*)(xp + t0);            // seg0: 16B aligned
        float2 b0 = *(const float2*)(xp + t0 + 50);       // seg1: 8B aligned
        float2 b1 = *(const float2*)(xp + t0 + 52);
        float4 c  = *(const float4*)(xp + t0 + 100);      // seg2: 16B aligned
        float xa[4] = {a.x, a.y, a.z, a.w};
        float xb[4] = {b0.x, b0.y, b1.x, b1.y};
        float xc[4] = {c.x, c.y, c.z, c.w};
        #pragma unroll
        for (int b = 0; b < NB; b++) {
            float4 w0 = *(const float4*)(trow + b * 200 + 2 * t0);      // t0,t0+1 (broadcast)
            float4 w1 = *(const float4*)(trow + b * 200 + 2 * t0 + 4);  // t0+2,t0+3
            float cs[4] = {w0.x, w0.z, w1.x, w1.z};
            float sn[4] = {w0.y, w0.w, w1.y, w1.w};
            #pragma unroll
            for (int u = 0; u < 4; u++) {
                re[b][0] += xa[u] * cs[u];  im[b][0] += xa[u] * sn[u];
                re[b][1] += xb[u] * cs[u];  im[b][1] += xb[u] * sn[u];
                re[b][2] += xc[u] * cs[u];  im[b][2] += xc[u] * sn[u];
            }
        }
    }

    // detrend: FFT(hann)[1] = -25, zero for k>=2 -> only bin k=1 corrected
    if (KB == 1) {
        re[0][0] += 25.f * mu0;
        re[0][1] += 25.f * mu1;
        re[0][2] += 25.f * mu2;
    }

    float s0 = 0.f, s1 = 0.f, s2 = 0.f, s3 = 0.f;
    #pragma unroll
    for (int b = 0; b < NB; b++) {
        int k = KB + b;
        float v = re[b][0] * re[b][0] + im[b][0] * im[b][0]
                + re[b][1] * re[b][1] + im[b][1] * im[b][1]
                + re[b][2] * re[b][2] + im[b][2] * im[b][2];
        if (k >= 1  && k <= 4)  s0 += v;
        if (k >= 4  && k <= 8)  s1 += v;
        if (k >= 8  && k <= 13) s2 += v;
        if (k >= 13)            s3 += v;
    }
    if (KB <= 4)                       atomicAdd(&bs[0], s0);
    if (KB <= 8 && KB + NB - 1 >= 4)   atomicAdd(&bs[1], s1);
    if (KB <= 13 && KB + NB - 1 >= 8)  atomicAdd(&bs[2], s2);
    if (KB + NB - 1 >= 13)             atomicAdd(&bs[3], s3);
}

// ---------------------------------------------------------------------------
// Kernel A: 512 threads = 8 waves, 64 pairs/block, lane = pair.
// wave0: stats + bins 1-2; waves 1..7: 4 bins each (3..30).
// ---------------------------------------------------------------------------
__global__ __launch_bounds__(512, 4) void kA(const float* __restrict__ x,
                                             const float2* __restrict__ tabg,
                                             float* __restrict__ avg,
                                             float* __restrict__ mxg,
                                             float* __restrict__ feat) {
    __shared__ __align__(16) float xs[PPB * XSTR];   // 52224 B
    __shared__ __align__(16) float tbf[6000];        // 24000 B
    __shared__ float bsum[PPB][4];                   // 1024 B

    const int tid = threadIdx.x;
    const int blk = blockIdx.x;

    // stage table (contiguous float4)
    {
        const float4* tg = (const float4*)tabg;
        float4* td = (float4*)tbf;
        for (int i = tid; i < 1500; i += 512) td[i] = tg[i];
    }
    // stage x: 64 rows * 200 floats, b128 writes into stride-204 rows
    {
        const float4* xg = (const float4*)(x + (size_t)blk * PPB * TT);
        for (int i = tid; i < 3200; i += 512) {
            float4 v = xg[i];
            int p = i / 50, t4 = (i % 50) * 4;
            *(float4*)(xs + p * XSTR + t4) = v;
        }
    }
    if (tid < 256) ((float*)bsum)[tid] = 0.f;
    __syncthreads();

    const int wv = tid >> 6, p = tid & 63;
    const float* xp = xs + p * XSTR;
    float* bs = bsum[p];

    float mu0 = 0.f, mu1 = 0.f, mu2 = 0.f;
    if (wv == 0) {
        // stats pre-pass: half-block sums h0..h3 (t in [0,50)[50,100)[100,150)[150,200)) + max
        float h0 = 0.f, h1 = 0.f, h2 = 0.f, h3 = 0.f, m = -3.4e38f;
        #pragma unroll
        for (int i = 0; i < 12; i++) {                     // t 0..47
            float4 v = *(const float4*)(xp + i * 4);
            h0 += (v.x + v.y) + (v.z + v.w);
            m = fmaxf(m, fmaxf(fmaxf(v.x, v.y), fmaxf(v.z, v.w)));
        }
        {   float4 v = *(const float4*)(xp + 48);          // t 48..51
            h0 += v.x + v.y; h1 += v.z + v.w;
            m = fmaxf(m, fmaxf(fmaxf(v.x, v.y), fmaxf(v.z, v.w))); }
        #pragma unroll
        for (int i = 13; i < 25; i++) {                    // t 52..99
            float4 v = *(const float4*)(xp + i * 4);
            h1 += (v.x + v.y) + (v.z + v.w);
            m = fmaxf(m, fmaxf(fmaxf(v.x, v.y), fmaxf(v.z, v.w)));
        }
        #pragma unroll
        for (int i = 25; i < 37; i++) {                    // t 100..147
            float4 v = *(const float4*)(xp + i * 4);
            h2 += (v.x + v.y) + (v.z + v.w);
            m = fmaxf(m, fmaxf(fmaxf(v.x, v.y), fmaxf(v.z, v.w)));
        }
        {   float4 v = *(const float4*)(xp + 148);         // t 148..151
            h2 += v.x + v.y; h3 += v.z + v.w;
            m = fmaxf(m, fmaxf(fmaxf(v.x, v.y), fmaxf(v.z, v.w))); }
        #pragma unroll
        for (int i = 38; i < 50; i++) {                    // t 152..199
            float4 v = *(const float4*)(xp + i * 4);
            h3 += (v.x + v.y) + (v.z + v.w);
            m = fmaxf(m, fmaxf(fmaxf(v.x, v.y), fmaxf(v.z, v.w)));
        }
        int pair = blk * PPB + p;
        avg[pair] = (h0 + h1 + h2 + h3) * (1.f / 200.f);
        mxg[pair] = m;
        mu0 = (h0 + h1) * 0.01f; mu1 = (h1 + h2) * 0.01f; mu2 = (h2 + h3) * 0.01f;
    }

    switch (wv) {
        case 0: dft_wave<1,  2>(xp, tbf, bs, mu0, mu1, mu2); break;
        case 1: dft_wave<3,  4>(xp, tbf, bs, 0, 0, 0); break;
        case 2: dft_wave<7,  4>(xp, tbf, bs, 0, 0, 0); break;
        case 3: dft_wave<11, 4>(xp, tbf, bs, 0, 0, 0); break;
        case 4: dft_wave<15, 4>(xp, tbf, bs, 0, 0, 0); break;
        case 5: dft_wave<19, 4>(xp, tbf, bs, 0, 0, 0); break;
        case 6: dft_wave<23, 4>(xp, tbf, bs, 0, 0, 0); break;
        default: dft_wave<27, 4>(xp, tbf, bs, 0, 0, 0); break;
    }

    __syncthreads();
    if (tid < 256) {
        int pp = tid >> 2, bb = tid & 3;
        const float cnt[4] = {4.f, 5.f, 6.f, 18.f};
        // psd scale: /(100*37.5), *2 one-sided, /3 segs, / band count
        feat[(size_t)(blk * PPB + pp) * 4 + bb] = bsum[pp][bb] * (2.f / (11250.f * cnt[bb]));
    }
}

// ---------------------------------------------------------------------------
// Kernel B: attention + MLP head. One batch row per block, 256 threads,
// K-split partial sums so every phase keeps all threads busy with short loops.
// 2048 blocks -> 8 blocks/CU -> 32 waves/CU for latency hiding.
// ---------------------------------------------------------------------------
__global__ __launch_bounds__(256, 8) void kB(const float* __restrict__ avg,
                                             const float* __restrict__ mxv,
                                             const float* __restrict__ feat,
                                             const float* __restrict__ w_att1,
                                             const float* __restrict__ w_att2,
                                             const float* __restrict__ w_bb,
                                             const float* __restrict__ b_bb,
                                             const float* __restrict__ w_fe1,
                                             const float* __restrict__ b_fe1,
                                             const float* __restrict__ w_fe2,
                                             const float* __restrict__ b_fe2,
                                             const float* __restrict__ w_h1,
                                             const float* __restrict__ b_h1,
                                             const float* __restrict__ w_h2,
                                             const float* __restrict__ b_h2,
                                             const float* __restrict__ w_h3,
                                             const float* __restrict__ b_h3,
                                             float* __restrict__ out) {
    __shared__ float s_avg[132], s_mx[132], s_fq[520];
    __shared__ float s_t1a[16], s_t1b[16], s_t1[16];
    __shared__ float s_v[132];
    __shared__ float s_tf[2][64];      // time_feat K-partials
    __shared__ float s_p1[2][128];     // f1 K-partials
    __shared__ float s_f1[128];
    __shared__ float s_p2[4][64];      // f2 K-partials
    __shared__ float s_h[128];         // concat [time_feat, f2]
    __shared__ float s_pg1[2][128];    // g1 K-partials
    __shared__ float s_g1[128];
    __shared__ float s_pg2[4][64];     // g2 K-partials

    const int b = blockIdx.x;
    const int tid = threadIdx.x;

    for (int i = tid; i < 129; i += 256) { s_avg[i] = avg[b * 129 + i]; s_mx[i] = mxv[b * 129 + i]; }
    for (int i = tid; i < 516; i += 256) s_fq[i] = feat[(size_t)b * 516 + i];
    __syncthreads();

    // att hidden partials: relu(avg@w1), relu(mx@w1)
    if (tid < 32) {
        int h = tid & 15;
        const float* src = (tid >= 16) ? s_mx : s_avg;
        float acc = 0.f;
        #pragma unroll 4
        for (int c = 0; c < 129; c++) acc += src[c] * w_att1[c * 16 + h];
        ((tid >= 16) ? s_t1b : s_t1a)[h] = fmaxf(acc, 0.f);
    }
    __syncthreads();
    if (tid < 16) s_t1[tid] = s_t1a[tid] + s_t1b[tid];
    __syncthreads();

    // att = sigmoid(hidden@w2); v = avg*att
    if (tid < 129) {
        float l = 0.f;
        #pragma unroll
        for (int j = 0; j < 16; j++) l += s_t1[j] * w_att2[j * 129 + tid];
        s_v[tid] = s_avg[tid] / (1.f + expf(-l));
    }
    __syncthreads();

    // time_feat partials: v@w_bb (129 -> 64), 2-way K-split
    if (tid < 128) {
        int o = tid & 63, ks = tid >> 6;
        int i0 = ks ? 65 : 0, i1 = ks ? 129 : 65;
        float acc = 0.f;
        #pragma unroll 4
        for (int i = i0; i < i1; i++) acc += s_v[i] * w_bb[i * 64 + o];
        s_tf[ks][o] = acc;
    }
    // f1 partials: fq@w_fe1 (516 -> 128), 2-way K-split, all 256 threads
    {
        int o = tid & 127, ks = tid >> 7;
        float acc = 0.f;
        #pragma unroll 4
        for (int i = ks * 258; i < ks * 258 + 258; i++) acc += s_fq[i] * w_fe1[i * 128 + o];
        s_p1[ks][o] = acc;
    }
    __syncthreads();
    if (tid < 64) s_h[tid] = fmaxf(s_tf[0][tid] + s_tf[1][tid] + b_bb[tid], 0.f);
    if (tid >= 128) { int o = tid - 128; s_f1[o] = fmaxf(s_p1[0][o] + s_p1[1][o] + b_fe1[o], 0.f); }
    __syncthreads();

    // f2 partials: f1@w_fe2 (128 -> 64), 4-way K-split
    {
        int o = tid & 63, ks = tid >> 6;
        float acc = 0.f;
        #pragma unroll 4
        for (int i = ks * 32; i < ks * 32 + 32; i++) acc += s_f1[i] * w_fe2[i * 64 + o];
        s_p2[ks][o] = acc;
    }
    __syncthreads();
    if (tid < 64) s_h[64 + tid] = fmaxf(s_p2[0][tid] + s_p2[1][tid] + s_p2[2][tid] + s_p2[3][tid] + b_fe2[tid], 0.f);
    __syncthreads();

    // g1 partials: h@w_h1 (128 -> 128), 2-way K-split
    {
        int o = tid & 127, ks = tid >> 7;
        float acc = 0.f;
        #pragma unroll 4
        for (int i = ks * 64; i < ks * 64 + 64; i++) acc += s_h[i] * w_h1[i * 128 + o];
        s_pg1[ks][o] = acc;
    }
    __syncthreads();
    if (tid < 128) s_g1[tid] = fmaxf(s_pg1[0][tid] + s_pg1[1][tid] + b_h1[tid], 0.f);
    __syncthreads();

    // g2 partials: g1@w_h2 (128 -> 64), 4-way K-split
    {
        int o = tid & 63, ks = tid >> 6;
        float acc = 0.f;
        #pragma unroll 4
        for (int i = ks * 32; i < ks * 32 + 32; i++) acc += s_g1[i] * w_h2[i * 64 + o];
        s_pg2[ks][o] = acc;
    }
    __syncthreads();

    // out = g2 . w_h3 + b_h3 (one wave)
    if (tid < 64) {
        float g2 = fmaxf(s_pg2[0][tid] + s_pg2[1][tid] + s_pg2[2][tid] + s_pg2[3][tid] + b_h2[tid], 0.f);
        float pz = g2 * w_h3[tid];
        for (int off = 32; off >= 1; off >>= 1) pz += __shfl_xor(pz, off, 64);
        if (tid == 0) out[b] = pz + b_h3[0];
    }
}

// ---------------------------------------------------------------------------
extern "C" void kernel_launch(void* const* d_in, const int* in_sizes, int n_in,
                              void* d_out, int out_size, void* d_ws, size_t ws_size,
                              hipStream_t stream) {
    const float* x      = (const float*)d_in[0];
    const float* w_att1 = (const float*)d_in[1];
    const float* w_att2 = (const float*)d_in[2];
    const float* w_bb   = (const float*)d_in[3];
    const float* b_bb   = (const float*)d_in[4];
    const float* w_fe1  = (const float*)d_in[5];
    const float* b_fe1  = (const float*)d_in[6];
    const float* w_fe2  = (const float*)d_in[7];
    const float* b_fe2  = (const float*)d_in[8];
    const float* w_h1   = (const float*)d_in[9];
    const float* b_h1   = (const float*)d_in[10];
    const float* w_h2   = (const float*)d_in[11];
    const float* b_h2   = (const float*)d_in[12];
    const float* w_h3   = (const float*)d_in[13];
    const float* b_h3   = (const float*)d_in[14];

    float* ws = (float*)d_ws;
    float2* tab = (float2*)ws;
    float* avg = ws + OFF_AVG;
    float* mxv = ws + OFF_MX;
    float* feat = ws + OFF_FT;

    kInit<<<12, 256, 0, stream>>>(tab);
    kA<<<NPAIR / PPB, 512, 0, stream>>>(x, (const float2*)tab, avg, mxv, feat);
    kB<<<BB, 256, 0, stream>>>(avg, mxv, feat,
                               w_att1, w_att2, w_bb, b_bb,
                               w_fe1, b_fe1, w_fe2, b_fe2,
                               w_h1, b_h1, w_h2, b_h2, w_h3, b_h3,
                               (float*)d_out);
}

// Round 4
// 508.385 us; speedup vs baseline: 1.1211x; 1.1211x over previous
//
#include <hip/hip_runtime.h>
#include <math.h>

// Problem constants
constexpr int BB = 2048;     // batch
constexpr int CC = 129;      // channels
constexpr int TT = 200;      // time
constexpr int NPAIR = BB * CC;          // 264192
constexpr int PPB = 64;                 // pairs per block in kA (lane = pair)
// x row stride in dwords: multiple of 4 (16B-aligned rows for b128 write/read)
constexpr int XSTR = 204;

// d_ws layout (in floats)
constexpr int OFF_AVG = 8192;                    // tab occupies 30*100*2 = 6000 floats
constexpr int OFF_MX  = OFF_AVG + NPAIR;
constexpr int OFF_FT  = OFF_MX + NPAIR;          // NPAIR*4 floats

// ---------------------------------------------------------------------------
// Init: windowed DFT table, tab[k-1][t] = (w[t]*cos(2pi*k*t/100), w[t]*sin(...)).
// ---------------------------------------------------------------------------
__global__ void kInit(float2* __restrict__ tab) {
    int i = blockIdx.x * 256 + threadIdx.x;
    if (i >= 3000) return;
    int r = i / 100, t = i % 100;
    int ph = ((r + 1) * t) % 100;                 // exact mod-100 reduction
    const float C = 0.06283185307179587f;         // 2*pi/100
    float w = 0.5f - 0.5f * cosf(C * (float)t);
    float ang = C * (float)ph;
    tab[i] = make_float2(w * cosf(ang), w * sinf(ang));
}

// ---------------------------------------------------------------------------
// DFT worker: one wave handles bins KB..KB+NB-1 for 64 pairs (lane = pair).
// x comes from LDS (per-lane rows); the table comes straight from GLOBAL
// memory with wave-uniform addresses -> scalar s_load (SMEM pipe) or at worst
// L1-resident VMEM. Keeps the single per-CU LDS pipe free for x reads
// (round-3 profiling showed the LDS pipe, not VALU, was the bound).
// ---------------------------------------------------------------------------
template<int KB, int NB>
__device__ __forceinline__ void dft_wave(const float* __restrict__ xp,
                                         const float* __restrict__ tabg,
                                         float* __restrict__ bs,
                                         float mu0, float mu1, float mu2) {
    const float* trow = tabg + (KB - 1) * 200;    // 200 floats (100 float2) per bin
    float re[NB][3], im[NB][3];
    #pragma unroll
    for (int b = 0; b < NB; b++)
        #pragma unroll
        for (int s = 0; s < 3; s++) { re[b][s] = 0.f; im[b][s] = 0.f; }

    #pragma unroll 5
    for (int t0 = 0; t0 < 100; t0 += 4) {
        float4 a  = *(const float4*)(xp + t0);            // LDS, 16B aligned
        float2 b0 = *(const float2*)(xp + t0 + 50);       // LDS, 8B aligned
        float2 b1 = *(const float2*)(xp + t0 + 52);
        float4 c  = *(const float4*)(xp + t0 + 100);      // LDS, 16B aligned
        float xa[4] = {a.x, a.y, a.z, a.w};
        float xb[4] = {b0.x, b0.y, b1.x, b1.y};
        float xc[4] = {c.x, c.y, c.z, c.w};
        #pragma unroll
        for (int b = 0; b < NB; b++) {
            // 8 consecutive floats, wave-uniform address -> s_load_dwordx8
            float4 w0 = *(const float4*)(trow + b * 200 + 2 * t0);
            float4 w1 = *(const float4*)(trow + b * 200 + 2 * t0 + 4);
            float cs[4] = {w0.x, w0.z, w1.x, w1.z};
            float sn[4] = {w0.y, w0.w, w1.y, w1.w};
            #pragma unroll
            for (int u = 0; u < 4; u++) {
                re[b][0] += xa[u] * cs[u];  im[b][0] += xa[u] * sn[u];
                re[b][1] += xb[u] * cs[u];  im[b][1] += xb[u] * sn[u];
                re[b][2] += xc[u] * cs[u];  im[b][2] += xc[u] * sn[u];
            }
        }
    }

    // detrend: FFT(hann)[1] = -25, zero for k>=2 -> only bin k=1 corrected
    if (KB == 1) {
        re[0][0] += 25.f * mu0;
        re[0][1] += 25.f * mu1;
        re[0][2] += 25.f * mu2;
    }

    float s0 = 0.f, s1 = 0.f, s2 = 0.f, s3 = 0.f;
    #pragma unroll
    for (int b = 0; b < NB; b++) {
        int k = KB + b;
        float v = re[b][0] * re[b][0] + im[b][0] * im[b][0]
                + re[b][1] * re[b][1] + im[b][1] * im[b][1]
                + re[b][2] * re[b][2] + im[b][2] * im[b][2];
        if (k >= 1  && k <= 4)  s0 += v;
        if (k >= 4  && k <= 8)  s1 += v;
        if (k >= 8  && k <= 13) s2 += v;
        if (k >= 13)            s3 += v;
    }
    if (KB <= 4)                       atomicAdd(&bs[0], s0);
    if (KB <= 8 && KB + NB - 1 >= 4)   atomicAdd(&bs[1], s1);
    if (KB <= 13 && KB + NB - 1 >= 8)  atomicAdd(&bs[2], s2);
    if (KB + NB - 1 >= 13)             atomicAdd(&bs[3], s3);
}

// ---------------------------------------------------------------------------
// Kernel A: 256 threads = 4 waves, 64 pairs/block, lane = pair.
// wave0: stats + bins 1-6; wave1: 7-14; wave2: 15-22; wave3: 23-30.
// LDS = x only (52 KB) -> 3 blocks/CU.
// ---------------------------------------------------------------------------
__global__ __launch_bounds__(256, 3) void kA(const float* __restrict__ x,
                                             const float* __restrict__ tabg,
                                             float* __restrict__ avg,
                                             float* __restrict__ mxg,
                                             float* __restrict__ feat) {
    __shared__ __align__(16) float xs[PPB * XSTR];   // 52224 B
    __shared__ float bsum[PPB][4];                   // 1024 B

    const int tid = threadIdx.x;
    const int blk = blockIdx.x;

    // stage x: 64 rows * 200 floats, b128 writes into stride-204 rows
    {
        const float4* xg = (const float4*)(x + (size_t)blk * PPB * TT);
        for (int i = tid; i < 3200; i += 256) {
            float4 v = xg[i];
            int p = i / 50, t4 = (i % 50) * 4;
            *(float4*)(xs + p * XSTR + t4) = v;
        }
    }
    ((float*)bsum)[tid] = 0.f;
    __syncthreads();

    const int wv = tid >> 6, p = tid & 63;
    const float* xp = xs + p * XSTR;
    float* bs = bsum[p];

    float mu0 = 0.f, mu1 = 0.f, mu2 = 0.f;
    if (wv == 0) {
        // stats pre-pass: half-sums h0..h3 over t[0,50)[50,100)[100,150)[150,200) + max
        float h0 = 0.f, h1 = 0.f, h2 = 0.f, h3 = 0.f, m = -3.4e38f;
        #pragma unroll
        for (int i = 0; i < 12; i++) {                     // t 0..47
            float4 v = *(const float4*)(xp + i * 4);
            h0 += (v.x + v.y) + (v.z + v.w);
            m = fmaxf(m, fmaxf(fmaxf(v.x, v.y), fmaxf(v.z, v.w)));
        }
        {   float4 v = *(const float4*)(xp + 48);          // t 48..51
            h0 += v.x + v.y; h1 += v.z + v.w;
            m = fmaxf(m, fmaxf(fmaxf(v.x, v.y), fmaxf(v.z, v.w))); }
        #pragma unroll
        for (int i = 13; i < 25; i++) {                    // t 52..99
            float4 v = *(const float4*)(xp + i * 4);
            h1 += (v.x + v.y) + (v.z + v.w);
            m = fmaxf(m, fmaxf(fmaxf(v.x, v.y), fmaxf(v.z, v.w)));
        }
        #pragma unroll
        for (int i = 25; i < 37; i++) {                    // t 100..147
            float4 v = *(const float4*)(xp + i * 4);
            h2 += (v.x + v.y) + (v.z + v.w);
            m = fmaxf(m, fmaxf(fmaxf(v.x, v.y), fmaxf(v.z, v.w)));
        }
        {   float4 v = *(const float4*)(xp + 148);         // t 148..151
            h2 += v.x + v.y; h3 += v.z + v.w;
            m = fmaxf(m, fmaxf(fmaxf(v.x, v.y), fmaxf(v.z, v.w))); }
        #pragma unroll
        for (int i = 38; i < 50; i++) {                    // t 152..199
            float4 v = *(const float4*)(xp + i * 4);
            h3 += (v.x + v.y) + (v.z + v.w);
            m = fmaxf(m, fmaxf(fmaxf(v.x, v.y), fmaxf(v.z, v.w)));
        }
        int pair = blk * PPB + p;
        avg[pair] = (h0 + h1 + h2 + h3) * (1.f / 200.f);
        mxg[pair] = m;
        mu0 = (h0 + h1) * 0.01f; mu1 = (h1 + h2) * 0.01f; mu2 = (h2 + h3) * 0.01f;
    }

    switch (wv) {
        case 0: dft_wave<1,  6>(xp, tabg, bs, mu0, mu1, mu2); break;
        case 1: dft_wave<7,  8>(xp, tabg, bs, 0, 0, 0); break;
        case 2: dft_wave<15, 8>(xp, tabg, bs, 0, 0, 0); break;
        default: dft_wave<23, 8>(xp, tabg, bs, 0, 0, 0); break;
    }

    __syncthreads();
    {
        int pp = tid >> 2, bb = tid & 3;
        const float cnt[4] = {4.f, 5.f, 6.f, 18.f};
        // psd scale: /(100*37.5), *2 one-sided, /3 segs, / band count
        feat[(size_t)(blk * PPB + pp) * 4 + bb] = bsum[pp][bb] * (2.f / (11250.f * cnt[bb]));
    }
}

// ---------------------------------------------------------------------------
// Kernel B: attention + MLP head. One batch row per block, 256 threads,
// K-split partial sums so every phase keeps all threads busy with short loops.
// ---------------------------------------------------------------------------
__global__ __launch_bounds__(256, 8) void kB(const float* __restrict__ avg,
                                             const float* __restrict__ mxv,
                                             const float* __restrict__ feat,
                                             const float* __restrict__ w_att1,
                                             const float* __restrict__ w_att2,
                                             const float* __restrict__ w_bb,
                                             const float* __restrict__ b_bb,
                                             const float* __restrict__ w_fe1,
                                             const float* __restrict__ b_fe1,
                                             const float* __restrict__ w_fe2,
                                             const float* __restrict__ b_fe2,
                                             const float* __restrict__ w_h1,
                                             const float* __restrict__ b_h1,
                                             const float* __restrict__ w_h2,
                                             const float* __restrict__ b_h2,
                                             const float* __restrict__ w_h3,
                                             const float* __restrict__ b_h3,
                                             float* __restrict__ out) {
    __shared__ float s_avg[132], s_mx[132], s_fq[520];
    __shared__ float s_t1a[16], s_t1b[16], s_t1[16];
    __shared__ float s_v[132];
    __shared__ float s_tf[2][64];      // time_feat K-partials
    __shared__ float s_p1[2][128];     // f1 K-partials
    __shared__ float s_f1[128];
    __shared__ float s_p2[4][64];      // f2 K-partials
    __shared__ float s_h[128];         // concat [time_feat, f2]
    __shared__ float s_pg1[2][128];    // g1 K-partials
    __shared__ float s_g1[128];
    __shared__ float s_pg2[4][64];     // g2 K-partials

    const int b = blockIdx.x;
    const int tid = threadIdx.x;

    for (int i = tid; i < 129; i += 256) { s_avg[i] = avg[b * 129 + i]; s_mx[i] = mxv[b * 129 + i]; }
    for (int i = tid; i < 516; i += 256) s_fq[i] = feat[(size_t)b * 516 + i];
    __syncthreads();

    // att hidden partials: relu(avg@w1), relu(mx@w1)
    if (tid < 32) {
        int h = tid & 15;
        const float* src = (tid >= 16) ? s_mx : s_avg;
        float acc = 0.f;
        #pragma unroll 4
        for (int c = 0; c < 129; c++) acc += src[c] * w_att1[c * 16 + h];
        ((tid >= 16) ? s_t1b : s_t1a)[h] = fmaxf(acc, 0.f);
    }
    __syncthreads();
    if (tid < 16) s_t1[tid] = s_t1a[tid] + s_t1b[tid];
    __syncthreads();

    // att = sigmoid(hidden@w2); v = avg*att
    if (tid < 129) {
        float l = 0.f;
        #pragma unroll
        for (int j = 0; j < 16; j++) l += s_t1[j] * w_att2[j * 129 + tid];
        s_v[tid] = s_avg[tid] / (1.f + expf(-l));
    }
    __syncthreads();

    // time_feat partials: v@w_bb (129 -> 64), 2-way K-split
    if (tid < 128) {
        int o = tid & 63, ks = tid >> 6;
        int i0 = ks ? 65 : 0, i1 = ks ? 129 : 65;
        float acc = 0.f;
        #pragma unroll 4
        for (int i = i0; i < i1; i++) acc += s_v[i] * w_bb[i * 64 + o];
        s_tf[ks][o] = acc;
    }
    // f1 partials: fq@w_fe1 (516 -> 128), 2-way K-split, all 256 threads
    {
        int o = tid & 127, ks = tid >> 7;
        float acc = 0.f;
        #pragma unroll 4
        for (int i = ks * 258; i < ks * 258 + 258; i++) acc += s_fq[i] * w_fe1[i * 128 + o];
        s_p1[ks][o] = acc;
    }
    __syncthreads();
    if (tid < 64) s_h[tid] = fmaxf(s_tf[0][tid] + s_tf[1][tid] + b_bb[tid], 0.f);
    if (tid >= 128) { int o = tid - 128; s_f1[o] = fmaxf(s_p1[0][o] + s_p1[1][o] + b_fe1[o], 0.f); }
    __syncthreads();

    // f2 partials: f1@w_fe2 (128 -> 64), 4-way K-split
    {
        int o = tid & 63, ks = tid >> 6;
        float acc = 0.f;
        #pragma unroll 4
        for (int i = ks * 32; i < ks * 32 + 32; i++) acc += s_f1[i] * w_fe2[i * 64 + o];
        s_p2[ks][o] = acc;
    }
    __syncthreads();
    if (tid < 64) s_h[64 + tid] = fmaxf(s_p2[0][tid] + s_p2[1][tid] + s_p2[2][tid] + s_p2[3][tid] + b_fe2[tid], 0.f);
    __syncthreads();

    // g1 partials: h@w_h1 (128 -> 128), 2-way K-split
    {
        int o = tid & 127, ks = tid >> 7;
        float acc = 0.f;
        #pragma unroll 4
        for (int i = ks * 64; i < ks * 64 + 64; i++) acc += s_h[i] * w_h1[i * 128 + o];
        s_pg1[ks][o] = acc;
    }
    __syncthreads();
    if (tid < 128) s_g1[tid] = fmaxf(s_pg1[0][tid] + s_pg1[1][tid] + b_h1[tid], 0.f);
    __syncthreads();

    // g2 partials: g1@w_h2 (128 -> 64), 4-way K-split
    {
        int o = tid & 63, ks = tid >> 6;
        float acc = 0.f;
        #pragma unroll 4
        for (int i = ks * 32; i < ks * 32 + 32; i++) acc += s_g1[i] * w_h2[i * 64 + o];
        s_pg2[ks][o] = acc;
    }
    __syncthreads();

    // out = g2 . w_h3 + b_h3 (one wave)
    if (tid < 64) {
        float g2 = fmaxf(s_pg2[0][tid] + s_pg2[1][tid] + s_pg2[2][tid] + s_pg2[3][tid] + b_h2[tid], 0.f);
        float pz = g2 * w_h3[tid];
        for (int off = 32; off >= 1; off >>= 1) pz += __shfl_xor(pz, off, 64);
        if (tid == 0) out[b] = pz + b_h3[0];
    }
}

// ---------------------------------------------------------------------------
extern "C" void kernel_launch(void* const* d_in, const int* in_sizes, int n_in,
                              void* d_out, int out_size, void* d_ws, size_t ws_size,
                              hipStream_t stream) {
    const float* x      = (const float*)d_in[0];
    const float* w_att1 = (const float*)d_in[1];
    const float* w_att2 = (const float*)d_in[2];
    const float* w_bb   = (const float*)d_in[3];
    const float* b_bb   = (const float*)d_in[4];
    const float* w_fe1  = (const float*)d_in[5];
    const float* b_fe1  = (const float*)d_in[6];
    const float* w_fe2  = (const float*)d_in[7];
    const float* b_fe2  = (const float*)d_in[8];
    const float* w_h1   = (const float*)d_in[9];
    const float* b_h1   = (const float*)d_in[10];
    const float* w_h2   = (const float*)d_in[11];
    const float* b_h2   = (const float*)d_in[12];
    const float* w_h3   = (const float*)d_in[13];
    const float* b_h3   = (const float*)d_in[14];

    float* ws = (float*)d_ws;
    float2* tab = (float2*)ws;
    float* avg = ws + OFF_AVG;
    float* mxv = ws + OFF_MX;
    float* feat = ws + OFF_FT;

    kInit<<<12, 256, 0, stream>>>(tab);
    kA<<<NPAIR / PPB, 256, 0, stream>>>(x, (const float*)tab, avg, mxv, feat);
    kB<<<BB, 256, 0, stream>>>(avg, mxv, feat,
                               w_att1, w_att2, w_bb, b_bb,
                               w_fe1, b_fe1, w_fe2, b_fe2,
                               w_h1, b_h1, w_h2, b_h2, w_h3, b_h3,
                               (float*)d_out);
}

// Round 5
// 474.071 us; speedup vs baseline: 1.2023x; 1.0724x over previous
//
#include <hip/hip_runtime.h>
#include <math.h>

// Problem constants
constexpr int BB = 2048;     // batch
constexpr int CC = 129;      // channels
constexpr int TT = 200;      // time
constexpr int NPAIR = BB * CC;          // 264192
constexpr int PPB = 64;                 // pairs per block in kA
constexpr int XSTR = 204;               // LDS x row stride (floats), 16B-aligned rows

// d_ws layout (in floats)
constexpr int OFF_AVG = 8192;           // B-frags occupy 16384 bf16 = 8192 floats
constexpr int OFF_MX  = OFF_AVG + NPAIR;
constexpr int OFF_FT  = OFF_MX + NPAIR; // NPAIR*4 floats

typedef __bf16 bf16x8 __attribute__((ext_vector_type(8)));
typedef float  f32x4  __attribute__((ext_vector_type(4)));

union BFU { int4 v; bf16x8 b; };
union BSU { __bf16 b; unsigned short u; };

// ---------------------------------------------------------------------------
// kInit: build W (128 k-rows x 64 n-cols) as MFMA B-fragments, split bf16
// hi/lo, pre-swizzled in fragment order:
//   bfr[((ks*4+nt)*2+h)*512 + lane*8 + i]  (ushort)
// Element (ks,nt,h,lane,i) = W[k = ks*32 + (lane>>4)*8 + i][n = nt*16 + (lane&15)]
//   n<60: bin kb=(n>>1)+1, even n -> w[t]*cos, odd n -> w[t]*sin (sign-free: im^2)
//   n==60: 1/100 (k<100)  -> GEMM emits segment mean (detrend + avg for free)
//   k>=100 or n>60: 0 (K padding / unused cols)
// ---------------------------------------------------------------------------
__global__ void kInit(unsigned short* __restrict__ bfr) {
    int tid = blockIdx.x * 256 + threadIdx.x;
    if (tid >= 16384) return;
    int i    = tid & 7;
    int lane = (tid >> 3) & 63;
    int h    = (tid >> 9) & 1;
    int nt   = (tid >> 10) & 3;
    int ks   = tid >> 12;
    int k = ks * 32 + (lane >> 4) * 8 + i;
    int n = nt * 16 + (lane & 15);
    float v = 0.f;
    if (k < 100) {
        if (n < 60) {
            int kb = (n >> 1) + 1;
            const float C = 0.06283185307179587f;      // 2*pi/100
            float w = 0.5f - 0.5f * cosf(C * (float)k);
            int ph = (kb * k) % 100;                   // exact phase reduction
            float ang = C * (float)ph;
            v = w * ((n & 1) ? sinf(ang) : cosf(ang));
        } else if (n == 60) {
            v = 0.01f;
        }
    }
    __bf16 hb = (__bf16)v;
    BSU out;
    if (h == 0) out.b = hb;
    else        out.b = (__bf16)(v - (float)hb);
    bfr[tid] = out.u;
}

// ---------------------------------------------------------------------------
// Kernel A: Welch via split-bf16 MFMA GEMM.
// 256 threads = 4 waves, 64 pairs/block -> 192 seg-rows = 12 M-tiles (3/wave).
// B (table) lives in VGPRs (32 frags); A built from LDS-staged fp32 x.
// spec = Ah*Bh + Ah*Bl + Al*Bh  (~2^-18 relative error).
// ---------------------------------------------------------------------------
__global__ __launch_bounds__(256, 2) void kA(const float* __restrict__ x,
                                             const unsigned short* __restrict__ bfr,
                                             float* __restrict__ avg,
                                             float* __restrict__ mxg,
                                             float* __restrict__ feat) {
    __shared__ __align__(16) float xs[PPB * XSTR + 32];   // 52.4 KB, doubles as spec buffer

    const int tid = threadIdx.x;
    const int blk = blockIdx.x;

    // ---- stage x: 64 rows x 200 floats into stride-204 rows (b128) ----
    {
        const float4* xg = (const float4*)(x + (size_t)blk * PPB * TT);
        #pragma unroll
        for (int it = 0; it < 13; it++) {
            int idx = tid + it * 256;
            if (idx < 3200) {
                float4 v = xg[idx];
                int p = idx / 50, t4 = (idx % 50) * 4;
                *(float4*)(xs + p * XSTR + t4) = v;
            }
        }
        // zero row pads (t 200..203) and the tail guard: seg2 K-pad reads land
        // here or in the next row's real data; must not be NaN (NaN*0 = NaN).
        if (tid < 64) *(float4*)(xs + tid * XSTR + 200) = float4{0.f, 0.f, 0.f, 0.f};
        if (tid < 32) xs[PPB * XSTR + tid] = 0.f;
    }

    // ---- load B fragments into registers (each wave holds the full table) ----
    bf16x8 Bh[4][4], Bl[4][4];
    {
        const int4* bg = (const int4*)bfr;    // frag f: 64 int4 (16B per lane)
        int ln = tid & 63;
        #pragma unroll
        for (int ks = 0; ks < 4; ks++)
            #pragma unroll
            for (int nt = 0; nt < 4; nt++) {
                BFU uh, ul;
                uh.v = bg[((ks * 4 + nt) * 2 + 0) * 64 + ln];
                ul.v = bg[((ks * 4 + nt) * 2 + 1) * 64 + ln];
                Bh[ks][nt] = uh.b;
                Bl[ks][nt] = ul.b;
            }
    }
    __syncthreads();

    // ---- max pass: 4 threads per pair, 50 samples each ----
    {
        int p = tid >> 2, q = tid & 3;
        const float* src = xs + p * XSTR + q * 50;
        float m = -3.4e38f;
        #pragma unroll
        for (int i = 0; i < 25; i++) {
            float2 v = *(const float2*)(src + i * 2);
            m = fmaxf(m, fmaxf(v.x, v.y));
        }
        m = fmaxf(m, __shfl_xor(m, 1, 64));
        m = fmaxf(m, __shfl_xor(m, 2, 64));
        if (q == 0) mxg[blk * PPB + p] = m;
    }

    // ---- MFMA: 3 M-tiles per wave ----
    const int wv = tid >> 6, lane = tid & 63;
    const int quad = lane >> 4, mrow = lane & 15;
    f32x4 acc[3][4];
    #pragma unroll
    for (int a = 0; a < 3; a++)
        #pragma unroll
        for (int b = 0; b < 4; b++) acc[a][b] = f32x4{0.f, 0.f, 0.f, 0.f};

    #pragma unroll
    for (int mi = 0; mi < 3; mi++) {
        int mt = wv * 3 + mi;
        int r = mt * 16 + mrow;                 // seg-row 0..191
        int pair = r / 3;
        int seg = r - pair * 3;
        const float* abase = xs + pair * XSTR + seg * 50 + quad * 8;
        #pragma unroll
        for (int ks = 0; ks < 4; ks++) {
            const float* s = abase + ks * 32;   // 8B-aligned (all terms even)
            float2 f0 = *(const float2*)(s);
            float2 f1 = *(const float2*)(s + 2);
            float2 f2 = *(const float2*)(s + 4);
            float2 f3 = *(const float2*)(s + 6);
            float f[8] = {f0.x, f0.y, f1.x, f1.y, f2.x, f2.y, f3.x, f3.y};
            bf16x8 Ah, Al;
            #pragma unroll
            for (int i = 0; i < 8; i++) {
                __bf16 hb = (__bf16)f[i];
                Ah[i] = hb;
                Al[i] = (__bf16)(f[i] - (float)hb);
            }
            #pragma unroll
            for (int nt = 0; nt < 4; nt++) {
                acc[mi][nt] = __builtin_amdgcn_mfma_f32_16x16x32_bf16(Al, Bh[ks][nt], acc[mi][nt], 0, 0, 0);
                acc[mi][nt] = __builtin_amdgcn_mfma_f32_16x16x32_bf16(Ah, Bl[ks][nt], acc[mi][nt], 0, 0, 0);
                acc[mi][nt] = __builtin_amdgcn_mfma_f32_16x16x32_bf16(Ah, Bh[ks][nt], acc[mi][nt], 0, 0, 0);
            }
        }
    }
    __syncthreads();

    // ---- write spec to LDS (reuse xs): sp[row][66], row=seg-row, col=j ----
    float* sp = xs;
    #pragma unroll
    for (int mi = 0; mi < 3; mi++) {
        int mt = wv * 3 + mi;
        #pragma unroll
        for (int nt = 0; nt < 4; nt++) {
            int col = nt * 16 + mrow;
            #pragma unroll
            for (int i = 0; i < 4; i++) {
                int row = mt * 16 + quad * 4 + i;    // C/D: col=lane&15, row=quad*4+reg
                sp[row * 66 + col] = acc[mi][nt][i];
            }
        }
    }
    __syncthreads();

    // ---- band reduce: thread = (pair, band) ----
    {
        int p = tid >> 2, bnd = tid & 3;
        const int c0[4] = {0, 6, 14, 24};
        const int c1[4] = {7, 15, 25, 59};   // inclusive; bins 4/8/13 in two bands
        float sum = 0.f;
        #pragma unroll
        for (int s = 0; s < 3; s++) {
            const float* row = sp + (p * 3 + s) * 66;
            float mu = row[60];
            int lo = c0[bnd];
            if (bnd == 0) {                   // detrend: re(k=1) += 25*mu
                float v = row[0] + 25.f * mu;
                sum += v * v;
                lo = 1;
            }
            for (int c = lo; c <= c1[bnd]; c++) {
                float v = row[c];
                sum += v * v;
            }
        }
        if (bnd == 0)
            avg[blk * PPB + p] = (sp[(p * 3) * 66 + 60] + sp[(p * 3 + 2) * 66 + 60]) * 0.5f;
        const float cnt[4] = {4.f, 5.f, 6.f, 18.f};
        feat[(size_t)(blk * PPB + p) * 4 + bnd] = sum * (2.f / (11250.f * cnt[bnd]));
    }
}

// ---------------------------------------------------------------------------
// Kernel B: attention + MLP head (unchanged from R4).
// ---------------------------------------------------------------------------
__global__ __launch_bounds__(256, 8) void kB(const float* __restrict__ avg,
                                             const float* __restrict__ mxv,
                                             const float* __restrict__ feat,
                                             const float* __restrict__ w_att1,
                                             const float* __restrict__ w_att2,
                                             const float* __restrict__ w_bb,
                                             const float* __restrict__ b_bb,
                                             const float* __restrict__ w_fe1,
                                             const float* __restrict__ b_fe1,
                                             const float* __restrict__ w_fe2,
                                             const float* __restrict__ b_fe2,
                                             const float* __restrict__ w_h1,
                                             const float* __restrict__ b_h1,
                                             const float* __restrict__ w_h2,
                                             const float* __restrict__ b_h2,
                                             const float* __restrict__ w_h3,
                                             const float* __restrict__ b_h3,
                                             float* __restrict__ out) {
    __shared__ float s_avg[132], s_mx[132], s_fq[520];
    __shared__ float s_t1a[16], s_t1b[16], s_t1[16];
    __shared__ float s_v[132];
    __shared__ float s_tf[2][64];
    __shared__ float s_p1[2][128];
    __shared__ float s_f1[128];
    __shared__ float s_p2[4][64];
    __shared__ float s_h[128];
    __shared__ float s_pg1[2][128];
    __shared__ float s_g1[128];
    __shared__ float s_pg2[4][64];

    const int b = blockIdx.x;
    const int tid = threadIdx.x;

    for (int i = tid; i < 129; i += 256) { s_avg[i] = avg[b * 129 + i]; s_mx[i] = mxv[b * 129 + i]; }
    for (int i = tid; i < 516; i += 256) s_fq[i] = feat[(size_t)b * 516 + i];
    __syncthreads();

    if (tid < 32) {
        int h = tid & 15;
        const float* src = (tid >= 16) ? s_mx : s_avg;
        float acc = 0.f;
        #pragma unroll 4
        for (int c = 0; c < 129; c++) acc += src[c] * w_att1[c * 16 + h];
        ((tid >= 16) ? s_t1b : s_t1a)[h] = fmaxf(acc, 0.f);
    }
    __syncthreads();
    if (tid < 16) s_t1[tid] = s_t1a[tid] + s_t1b[tid];
    __syncthreads();

    if (tid < 129) {
        float l = 0.f;
        #pragma unroll
        for (int j = 0; j < 16; j++) l += s_t1[j] * w_att2[j * 129 + tid];
        s_v[tid] = s_avg[tid] / (1.f + expf(-l));
    }
    __syncthreads();

    if (tid < 128) {
        int o = tid & 63, ks = tid >> 6;
        int i0 = ks ? 65 : 0, i1 = ks ? 129 : 65;
        float acc = 0.f;
        #pragma unroll 4
        for (int i = i0; i < i1; i++) acc += s_v[i] * w_bb[i * 64 + o];
        s_tf[ks][o] = acc;
    }
    {
        int o = tid & 127, ks = tid >> 7;
        float acc = 0.f;
        #pragma unroll 4
        for (int i = ks * 258; i < ks * 258 + 258; i++) acc += s_fq[i] * w_fe1[i * 128 + o];
        s_p1[ks][o] = acc;
    }
    __syncthreads();
    if (tid < 64) s_h[tid] = fmaxf(s_tf[0][tid] + s_tf[1][tid] + b_bb[tid], 0.f);
    if (tid >= 128) { int o = tid - 128; s_f1[o] = fmaxf(s_p1[0][o] + s_p1[1][o] + b_fe1[o], 0.f); }
    __syncthreads();

    {
        int o = tid & 63, ks = tid >> 6;
        float acc = 0.f;
        #pragma unroll 4
        for (int i = ks * 32; i < ks * 32 + 32; i++) acc += s_f1[i] * w_fe2[i * 64 + o];
        s_p2[ks][o] = acc;
    }
    __syncthreads();
    if (tid < 64) s_h[64 + tid] = fmaxf(s_p2[0][tid] + s_p2[1][tid] + s_p2[2][tid] + s_p2[3][tid] + b_fe2[tid], 0.f);
    __syncthreads();

    {
        int o = tid & 127, ks = tid >> 7;
        float acc = 0.f;
        #pragma unroll 4
        for (int i = ks * 64; i < ks * 64 + 64; i++) acc += s_h[i] * w_h1[i * 128 + o];
        s_pg1[ks][o] = acc;
    }
    __syncthreads();
    if (tid < 128) s_g1[tid] = fmaxf(s_pg1[0][tid] + s_pg1[1][tid] + b_h1[tid], 0.f);
    __syncthreads();

    {
        int o = tid & 63, ks = tid >> 6;
        float acc = 0.f;
        #pragma unroll 4
        for (int i = ks * 32; i < ks * 32 + 32; i++) acc += s_g1[i] * w_h2[i * 64 + o];
        s_pg2[ks][o] = acc;
    }
    __syncthreads();

    if (tid < 64) {
        float g2 = fmaxf(s_pg2[0][tid] + s_pg2[1][tid] + s_pg2[2][tid] + s_pg2[3][tid] + b_h2[tid], 0.f);
        float pz = g2 * w_h3[tid];
        for (int off = 32; off >= 1; off >>= 1) pz += __shfl_xor(pz, off, 64);
        if (tid == 0) out[b] = pz + b_h3[0];
    }
}

// ---------------------------------------------------------------------------
extern "C" void kernel_launch(void* const* d_in, const int* in_sizes, int n_in,
                              void* d_out, int out_size, void* d_ws, size_t ws_size,
                              hipStream_t stream) {
    const float* x      = (const float*)d_in[0];
    const float* w_att1 = (const float*)d_in[1];
    const float* w_att2 = (const float*)d_in[2];
    const float* w_bb   = (const float*)d_in[3];
    const float* b_bb   = (const float*)d_in[4];
    const float* w_fe1  = (const float*)d_in[5];
    const float* b_fe1  = (const float*)d_in[6];
    const float* w_fe2  = (const float*)d_in[7];
    const float* b_fe2  = (const float*)d_in[8];
    const float* w_h1   = (const float*)d_in[9];
    const float* b_h1   = (const float*)d_in[10];
    const float* w_h2   = (const float*)d_in[11];
    const float* b_h2   = (const float*)d_in[12];
    const float* w_h3   = (const float*)d_in[13];
    const float* b_h3   = (const float*)d_in[14];

    float* ws = (float*)d_ws;
    unsigned short* bfr = (unsigned short*)ws;     // 16384 bf16 = 8192 floats
    float* avg = ws + OFF_AVG;
    float* mxv = ws + OFF_MX;
    float* feat = ws + OFF_FT;

    kInit<<<64, 256, 0, stream>>>(bfr);
    kA<<<NPAIR / PPB, 256, 0, stream>>>(x, bfr, avg, mxv, feat);
    kB<<<BB, 256, 0, stream>>>(avg, mxv, feat,
                               w_att1, w_att2, w_bb, b_bb,
                               w_fe1, b_fe1, w_fe2, b_fe2,
                               w_h1, b_h1, w_h2, b_h2, w_h3, b_h3,
                               (float*)d_out);
}